// Round 12
// baseline (159.153 us; speedup 1.0000x reference)
//
#include <hip/hip_runtime.h>

#define NB 8
#define NS 2048
#define ND 64
#define LOG2E 1.44269504f

typedef _Float16 half8 __attribute__((ext_vector_type(8)));
typedef __attribute__((ext_vector_type(4))) float floatx4;

__device__ __forceinline__ half8 cvt8(const float* p) {
    float4 a = *(const float4*)p;
    float4 b = *(const float4*)(p + 4);
    half8 h = {(_Float16)a.x, (_Float16)a.y, (_Float16)a.z, (_Float16)a.w,
               (_Float16)b.x, (_Float16)b.y, (_Float16)b.z, (_Float16)b.w};
    return h;
}
// column read of row-major W[64][64]: 8 fp32 at stride 64, cast fp16
__device__ __forceinline__ half8 cvtWcol(const float* base) {
    half8 h;
#pragma unroll
    for (int j = 0; j < 8; ++j) h[j] = (_Float16)base[j * 64];
    return h;
}

// ---------------- QKV projection via fp16 MFMA (r9 verbatim; XCD-aligned) -----
__global__ __launch_bounds__(256) void qkv_proj(
    const float* __restrict__ x,
    const float* __restrict__ Wq, const float* __restrict__ bq,
    const float* __restrict__ Wk, const float* __restrict__ bk,
    const float* __restrict__ Wv, const float* __restrict__ bv,
    _Float16* __restrict__ Qg, _Float16* __restrict__ Kg,
    _Float16* __restrict__ Vt)
{
    __shared__ _Float16 vt[64 * 18];

    const int tid  = threadIdx.x;
    const int wv   = tid >> 6;
    const int l    = tid & 63;
    const int quad = l >> 4;
    const int tx   = l & 15;

    const int b  = blockIdx.x & 7;
    const int n0 = (blockIdx.x >> 3) * 16;

    const float* xr = x + ((size_t)b * NS + n0 + tx) * ND + quad * 8;
    half8 a0 = cvt8(xr);
    half8 a1 = cvt8(xr + 32);

    const floatx4 zf = {0.f, 0.f, 0.f, 0.f};

#pragma unroll
    for (int i = 0; i < 3; ++i) {
        const int ct = wv * 3 + i;            // 0..11, wave-uniform
        const int m  = ct >> 2;
        const int lcol = (ct & 3) * 16 + tx;

        const float* Wm;
        const float* Bm;
        if (m == 0)      { Wm = Wq; Bm = bq; }
        else if (m == 1) { Wm = Wk; Bm = bk; }
        else             { Wm = Wv; Bm = bv; }

        half8 b0 = cvtWcol(Wm + (quad * 8) * 64 + lcol);
        half8 b1 = cvtWcol(Wm + (32 + quad * 8) * 64 + lcol);

        floatx4 acc = __builtin_amdgcn_mfma_f32_16x16x32_f16(a0, b0, zf, 0, 0, 0);
        acc = __builtin_amdgcn_mfma_f32_16x16x32_f16(a1, b1, acc, 0, 0, 0);
        const float bias = Bm[lcol];

        if (m == 0) {
#pragma unroll
            for (int r = 0; r < 4; ++r)
                Qg[((size_t)b * NS + n0 + quad * 4 + r) * ND + lcol] =
                    (_Float16)((acc[r] + bias) * LOG2E);
        } else if (m == 1) {
#pragma unroll
            for (int r = 0; r < 4; ++r)
                Kg[((size_t)b * NS + n0 + quad * 4 + r) * ND + lcol] = (_Float16)(acc[r] + bias);
        } else {
#pragma unroll
            for (int r = 0; r < 4; ++r)
                vt[lcol * 18 + quad * 4 + r] = (_Float16)(acc[r] + bias);
        }
    }
    __syncthreads();
    {
        const int d = tid >> 2, seg = tid & 3;
        uint2 p = *(uint2*)&vt[d * 18 + seg * 4];
        *(uint2*)(Vt + ((size_t)b * ND + d) * NS + n0 + seg * 4) = p;
    }
}

// ---------------- fused masked attention: 64 q-rows/block, traffic-minimal ----
// grid: 256 blocks = 1/CU (b = blk&7, q-group = blk>>3), 512 thr = 8 waves =
// 4 q-subtiles (qs) x 2 key-halves (kh). Each wave: 16 q-rows x 1024 keys.
// Two-pass recompute (no e-cache => no spill): pass 1 l = sum 2^s; mask
// e > l/N <=> p > mean(p) = 1/N; pass 2 recompute s, mask, LDS transpose, PV.
// K/V traffic: 768 KB/block x 256 = 192 MB total (vs 512 MB at 16-row blocks).
// The 4 qs-waves read identical K/V lines in lockstep -> L1 dedup.
__global__ __launch_bounds__(512, 4) void attn(
    const _Float16* __restrict__ Qg,
    const _Float16* __restrict__ Kg,
    const _Float16* __restrict__ Vt,
    float* __restrict__ out)
{
    // obuf: 128 rows x 68 stride fp32 = 34816 B; pbuf union: 8 x 16 x 76 fp16 = 19456 B
    __shared__ __align__(16) unsigned char smraw[128 * 68 * 4];
    __shared__ float lsh[128];
    _Float16* pbuf = (_Float16*)smraw;
    float*    obuf = (float*)smraw;

    const int tid  = threadIdx.x;
    const int wv   = tid >> 6;
    const int l    = tid & 63;
    const int quad = l >> 4;
    const int tx   = l & 15;
    const int qs   = wv & 3;        // q-subtile (16 rows)
    const int kh   = wv >> 2;       // key half (1024 keys)

    const int b  = blockIdx.x & 7;
    const int q0 = (blockIdx.x >> 3) * 64;

    const _Float16* Qb = Qg + ((size_t)b * NS + q0 + qs * 16) * ND;
    const _Float16* Kb = Kg + ((size_t)b * NS + kh * 1024) * ND;
    const _Float16* Vb = Vt + (size_t)b * ND * NS + kh * 1024;

    half8 qf0 = *(const half8*)(Qb + (size_t)tx * ND + quad * 8);
    half8 qf1 = *(const half8*)(Qb + (size_t)tx * ND + 32 + quad * 8);

    const floatx4 zf = {0.f, 0.f, 0.f, 0.f};

    // ---- pass 1: l = sum 2^s over 64 independent 16-key subtiles ----
    float lacc[4] = {0.f, 0.f, 0.f, 0.f};
#pragma unroll 8
    for (int s = 0; s < 64; ++s) {
        const _Float16* Kr = Kb + (size_t)(s * 16 + tx) * ND + quad * 8;
        half8 k0 = *(const half8*)Kr;
        half8 k1 = *(const half8*)(Kr + 32);
        floatx4 c = __builtin_amdgcn_mfma_f32_16x16x32_f16(qf0, k0, zf, 0, 0, 0);
        c = __builtin_amdgcn_mfma_f32_16x16x32_f16(qf1, k1, c, 0, 0, 0);
#pragma unroll
        for (int r = 0; r < 4; ++r)
            lacc[r] += __builtin_amdgcn_exp2f(c[r]);
    }
#pragma unroll
    for (int off = 1; off < 16; off <<= 1)
#pragma unroll
        for (int r = 0; r < 4; ++r)
            lacc[r] += __shfl_xor(lacc[r], off);
    if (tx == 0) {
#pragma unroll
        for (int r = 0; r < 4; ++r)
            lsh[wv * 16 + quad * 4 + r] = lacc[r];
    }
    __syncthreads();

    float inv[4], thr[4];
#pragma unroll
    for (int r = 0; r < 4; ++r) {
        const int row = quad * 4 + r;
        float L = lsh[qs * 16 + row] + lsh[(qs + 4) * 16 + row];
        inv[r] = 1.f / L;
        thr[r] = L * (1.f / (float)NS);
    }

    // ---- pass 2: 16 tiles of 64 keys: recompute s, mask, LDS transpose, PV ----
    floatx4 o[4] = {zf, zf, zf, zf};
    _Float16* pb = pbuf + wv * (16 * 76);

    for (int t = 0; t < 16; ++t) {
        const int kb = t * 64;
        half8 vf[4][2];
#pragma unroll
        for (int nt = 0; nt < 4; ++nt) {   // V early: consumed after LDS round-trip
            const _Float16* Vr = Vb + (size_t)(nt * 16 + tx) * NS + kb + quad * 8;
            vf[nt][0] = *(const half8*)Vr;
            vf[nt][1] = *(const half8*)(Vr + 32);
        }
#pragma unroll
        for (int nt = 0; nt < 4; ++nt) {
            const _Float16* Kr = Kb + (size_t)(kb + nt * 16 + tx) * ND + quad * 8;
            half8 k0 = *(const half8*)Kr;
            half8 k1 = *(const half8*)(Kr + 32);
            floatx4 c = __builtin_amdgcn_mfma_f32_16x16x32_f16(qf0, k0, zf, 0, 0, 0);
            c = __builtin_amdgcn_mfma_f32_16x16x32_f16(qf1, k1, c, 0, 0, 0);
#pragma unroll
            for (int r = 0; r < 4; ++r) {
                float e = __builtin_amdgcn_exp2f(c[r]);
                float w = (e > thr[r]) ? e * inv[r] : 0.f;
                pb[(quad * 4 + r) * 76 + nt * 16 + tx] = (_Float16)w;
            }
        }
        // per-wave DS FIFO ordering: these reads see this wave's writes above
        half8 af0 = *(const half8*)(pb + tx * 76 + quad * 8);
        half8 af1 = *(const half8*)(pb + tx * 76 + 32 + quad * 8);
#pragma unroll
        for (int nt = 0; nt < 4; ++nt)
            o[nt] = __builtin_amdgcn_mfma_f32_16x16x32_f16(af0, vf[nt][0], o[nt], 0, 0, 0);
#pragma unroll
        for (int nt = 0; nt < 4; ++nt)
            o[nt] = __builtin_amdgcn_mfma_f32_16x16x32_f16(af1, vf[nt][1], o[nt], 0, 0, 0);
    }

    __syncthreads();   // all pbuf reads complete before obuf reuse
#pragma unroll
    for (int nt = 0; nt < 4; ++nt)
#pragma unroll
        for (int r = 0; r < 4; ++r)
            obuf[(wv * 16 + quad * 4 + r) * 68 + nt * 16 + tx] = o[nt][r];
    __syncthreads();

    {   // merge kh pair, store: thread -> (row 0..63, 8 cols)
        const int row = tid >> 3;            // 0..63
        const int c8  = (tid & 7) * 8;
        const int sq  = row >> 4;            // q-subtile of this row
        const int rl  = row & 15;
        const float* s0p = &obuf[(sq * 16 + rl) * 68 + c8];        // kh = 0 partial
        const float* s1p = &obuf[((sq + 4) * 16 + rl) * 68 + c8];  // kh = 1 partial
        float4 a0 = *(const float4*)s0p;
        float4 a1 = *(const float4*)(s0p + 4);
        float4 b0 = *(const float4*)s1p;
        float4 b1 = *(const float4*)(s1p + 4);
        float4 r0 = {a0.x + b0.x, a0.y + b0.y, a0.z + b0.z, a0.w + b0.w};
        float4 r1 = {a1.x + b1.x, a1.y + b1.y, a1.z + b1.z, a1.w + b1.w};
        float* dst = out + ((size_t)b * NS + q0 + row) * ND + c8;
        *(float4*)dst = r0;
        *(float4*)(dst + 4) = r1;
    }
}

extern "C" void kernel_launch(void* const* d_in, const int* in_sizes, int n_in,
                              void* d_out, int out_size, void* d_ws, size_t ws_size,
                              hipStream_t stream) {
    const float* x  = (const float*)d_in[0];
    const float* Wq = (const float*)d_in[1];
    const float* bq = (const float*)d_in[2];
    const float* Wk = (const float*)d_in[3];
    const float* bk = (const float*)d_in[4];
    const float* Wv = (const float*)d_in[5];
    const float* bv = (const float*)d_in[6];

    _Float16* Qg = (_Float16*)d_ws;
    _Float16* Kg = Qg + (size_t)NB * NS * ND;
    _Float16* Vt = Kg + (size_t)NB * NS * ND;

    qkv_proj<<<NB * (NS / 16), 256, 0, stream>>>(x, Wq, bq, Wk, bk, Wv, bv, Qg, Kg, Vt);
    attn<<<NB * (NS / 64), 512, 0, stream>>>(Qg, Kg, Vt, (float*)d_out);
}

// Round 13
// 106.870 us; speedup vs baseline: 1.4892x; 1.4892x over previous
//
#include <hip/hip_runtime.h>

#define NB 8
#define NS 2048
#define ND 64
#define LOG2E 1.44269504f

typedef _Float16 half8 __attribute__((ext_vector_type(8)));
typedef __attribute__((ext_vector_type(4))) float floatx4;

__device__ __forceinline__ half8 cvt8(const float* p) {
    float4 a = *(const float4*)p;
    float4 b = *(const float4*)(p + 4);
    half8 h = {(_Float16)a.x, (_Float16)a.y, (_Float16)a.z, (_Float16)a.w,
               (_Float16)b.x, (_Float16)b.y, (_Float16)b.z, (_Float16)b.w};
    return h;
}
__device__ __forceinline__ half8 cvtWcol(const float* base) {
    half8 h;
#pragma unroll
    for (int j = 0; j < 8; ++j) h[j] = (_Float16)base[j * 64];
    return h;
}

// ---------------- QKV projection via fp16 MFMA (r9 verbatim; XCD-aligned) -----
__global__ __launch_bounds__(256) void qkv_proj(
    const float* __restrict__ x,
    const float* __restrict__ Wq, const float* __restrict__ bq,
    const float* __restrict__ Wk, const float* __restrict__ bk,
    const float* __restrict__ Wv, const float* __restrict__ bv,
    _Float16* __restrict__ Qg, _Float16* __restrict__ Kg,
    _Float16* __restrict__ Vt)
{
    __shared__ _Float16 vt[64 * 18];

    const int tid  = threadIdx.x;
    const int wv   = tid >> 6;
    const int l    = tid & 63;
    const int quad = l >> 4;
    const int tx   = l & 15;

    const int b  = blockIdx.x & 7;
    const int n0 = (blockIdx.x >> 3) * 16;

    const float* xr = x + ((size_t)b * NS + n0 + tx) * ND + quad * 8;
    half8 a0 = cvt8(xr);
    half8 a1 = cvt8(xr + 32);

    const floatx4 zf = {0.f, 0.f, 0.f, 0.f};

#pragma unroll
    for (int i = 0; i < 3; ++i) {
        const int ct = wv * 3 + i;
        const int m  = ct >> 2;
        const int lcol = (ct & 3) * 16 + tx;

        const float* Wm;
        const float* Bm;
        if (m == 0)      { Wm = Wq; Bm = bq; }
        else if (m == 1) { Wm = Wk; Bm = bk; }
        else             { Wm = Wv; Bm = bv; }

        half8 b0 = cvtWcol(Wm + (quad * 8) * 64 + lcol);
        half8 b1 = cvtWcol(Wm + (32 + quad * 8) * 64 + lcol);

        floatx4 acc = __builtin_amdgcn_mfma_f32_16x16x32_f16(a0, b0, zf, 0, 0, 0);
        acc = __builtin_amdgcn_mfma_f32_16x16x32_f16(a1, b1, acc, 0, 0, 0);
        const float bias = Bm[lcol];

        if (m == 0) {
#pragma unroll
            for (int r = 0; r < 4; ++r)
                Qg[((size_t)b * NS + n0 + quad * 4 + r) * ND + lcol] =
                    (_Float16)((acc[r] + bias) * LOG2E);
        } else if (m == 1) {
#pragma unroll
            for (int r = 0; r < 4; ++r)
                Kg[((size_t)b * NS + n0 + quad * 4 + r) * ND + lcol] = (_Float16)(acc[r] + bias);
        } else {
#pragma unroll
            for (int r = 0; r < 4; ++r)
                vt[lcol * 18 + quad * 4 + r] = (_Float16)(acc[r] + bias);
        }
    }
    __syncthreads();
    {
        const int d = tid >> 2, seg = tid & 3;
        uint2 p = *(uint2*)&vt[d * 18 + seg * 4];
        *(uint2*)(Vt + ((size_t)b * ND + d) * NS + n0 + seg * 4) = p;
    }
}

// ---------------- fused masked attention: LDS-staged K/V, barrier pipeline ----
// grid: 256 blocks (b = blk&7 XCD-pinned, 64 q-rows), 512 thr = 8 waves =
// 2 q-halves (h: 32 rows) x 4 key-quarters (kq: 16 keys/tile; 16 dims in PV).
// K/V stream through double-buffered LDS tiles (64 keys each): every thread
// stages 16B/tile; waves consume from LDS (conflict-tuned 144B row stride).
// Pass 1: l = sum 2^s. Mask: e > l/N <=> p > mean(p) = 1/N. Pass 2: recompute
// s from LDS K, P -> LDS exchange, PV from LDS V^T. Dims split by kq -> no
// partial-O merge. Per-wave global dependent-load chains: eliminated.
__global__ __launch_bounds__(512, 2) void attn(
    const _Float16* __restrict__ Qg,
    const _Float16* __restrict__ Kg,
    const _Float16* __restrict__ Vt,
    float* __restrict__ out)
{
    __shared__ _Float16 ksm[2 * 64 * 72];   // [buf][key][72]  (144B rows)
    __shared__ _Float16 vsm[2 * 64 * 72];   // [buf][dim][72]  (V^T tile)
    __shared__ _Float16 psm[64 * 72];       // P exchange [row][72]
    __shared__ float lsh[256];              // per-kq row denominators

    const int tid  = threadIdx.x;
    const int wv   = tid >> 6;
    const int l    = tid & 63;
    const int quad = l >> 4;
    const int tx   = l & 15;
    const int h    = wv >> 2;       // q-half (32 rows)
    const int kq   = wv & 3;        // key-quarter / dim-quarter

    const int b  = blockIdx.x & 7;
    const int q0 = (blockIdx.x >> 3) * 64;

    const _Float16* Qb = Qg + ((size_t)b * NS + q0 + h * 32) * ND;
    const _Float16* Kb = Kg + (size_t)b * NS * ND;
    const _Float16* Vb = Vt + (size_t)b * ND * NS;

    // Q A-frags: rows h*32 + rt*16 + tx, k-chunks 0/1
    half8 qf[2][2];
#pragma unroll
    for (int rt = 0; rt < 2; ++rt)
#pragma unroll
        for (int kc = 0; kc < 2; ++kc)
            qf[rt][kc] = *(const half8*)(Qb + (size_t)(rt * 16 + tx) * ND + kc * 32 + quad * 8);

    // staging roles: thread -> 16B of the 8KB tile
    const int skey = tid >> 3;              // key (K) or dim (V)
    const int sc   = (tid & 7) * 8;         // half offset within row
    const _Float16* Ksrc = Kb + (size_t)skey * ND + sc;   // + t*64*ND
    const _Float16* Vsrc = Vb + (size_t)skey * NS + sc;   // + t*64
    const int sdst = skey * 72 + sc;

    const floatx4 zf = {0.f, 0.f, 0.f, 0.f};
    const int krow = (kq * 16 + tx) * 72;   // K/V fragment row base (halfs)

    // ================= pass 1: l = sum 2^s =================
    float lacc[2][4] = {{0.f,0.f,0.f,0.f},{0.f,0.f,0.f,0.f}};
    {
        uint4 gk = *(const uint4*)Ksrc;            // tile 0
        *(uint4*)(ksm + sdst) = gk;
        for (int t = 0; t < 32; ++t) {
            const int buf = (t & 1) * 4608;
            __syncthreads();                        // tile t staged & visible
            if (t < 31) gk = *(const uint4*)(Ksrc + (size_t)(t + 1) * 64 * ND);
            half8 kf0 = *(const half8*)(ksm + buf + krow + quad * 8);
            half8 kf1 = *(const half8*)(ksm + buf + krow + 32 + quad * 8);
#pragma unroll
            for (int rt = 0; rt < 2; ++rt) {
                floatx4 c = __builtin_amdgcn_mfma_f32_16x16x32_f16(qf[rt][0], kf0, zf, 0, 0, 0);
                c = __builtin_amdgcn_mfma_f32_16x16x32_f16(qf[rt][1], kf1, c, 0, 0, 0);
#pragma unroll
                for (int r = 0; r < 4; ++r)
                    lacc[rt][r] += __builtin_amdgcn_exp2f(c[r]);
            }
            if (t < 31) *(uint4*)(ksm + (buf ^ 4608) + sdst) = gk;
        }
    }
    // reduce over the 16 key-lanes; publish per (kq, row)
#pragma unroll
    for (int off = 1; off < 16; off <<= 1)
#pragma unroll
        for (int rt = 0; rt < 2; ++rt)
#pragma unroll
            for (int r = 0; r < 4; ++r)
                lacc[rt][r] += __shfl_xor(lacc[rt][r], off);
    if (tx == 0) {
#pragma unroll
        for (int rt = 0; rt < 2; ++rt)
#pragma unroll
            for (int r = 0; r < 4; ++r)
                lsh[kq * 64 + h * 32 + rt * 16 + quad * 4 + r] = lacc[rt][r];
    }

    // pass-2 tile-0 loads overlap the merge barrier
    uint4 gk2 = *(const uint4*)Ksrc;
    uint4 gv  = *(const uint4*)Vsrc;
    __syncthreads();                                // lsh ready; pass-1 LDS reads done

    float inv[2][4], thr[2][4];
#pragma unroll
    for (int rt = 0; rt < 2; ++rt)
#pragma unroll
        for (int r = 0; r < 4; ++r) {
            const int row = h * 32 + rt * 16 + quad * 4 + r;
            float L = lsh[row] + lsh[64 + row] + lsh[128 + row] + lsh[192 + row];
            inv[rt][r] = 1.f / L;
            thr[rt][r] = L * (1.f / (float)NS);
        }

    // ================= pass 2: P + PV =================
    *(uint4*)(ksm + sdst) = gk2;
    *(uint4*)(vsm + sdst) = gv;
    floatx4 o[2] = {zf, zf};

    for (int t = 0; t < 32; ++t) {
        const int buf = (t & 1) * 4608;
        __syncthreads();                            // B1: tiles staged; psm free
        if (t < 31) {
            gk2 = *(const uint4*)(Ksrc + (size_t)(t + 1) * 64 * ND);
            gv  = *(const uint4*)(Vsrc + (size_t)(t + 1) * 64);
        }
        // QK from LDS, mask+normalize, P -> psm
        half8 kf0 = *(const half8*)(ksm + buf + krow + quad * 8);
        half8 kf1 = *(const half8*)(ksm + buf + krow + 32 + quad * 8);
#pragma unroll
        for (int rt = 0; rt < 2; ++rt) {
            floatx4 c = __builtin_amdgcn_mfma_f32_16x16x32_f16(qf[rt][0], kf0, zf, 0, 0, 0);
            c = __builtin_amdgcn_mfma_f32_16x16x32_f16(qf[rt][1], kf1, c, 0, 0, 0);
#pragma unroll
            for (int r = 0; r < 4; ++r) {
                float e = __builtin_amdgcn_exp2f(c[r]);
                float w = (e > thr[rt][r]) ? e * inv[rt][r] : 0.f;
                psm[(h * 32 + rt * 16 + quad * 4 + r) * 72 + kq * 16 + tx] = (_Float16)w;
            }
        }
        __syncthreads();                            // B2: psm complete
        // PV: A from psm, B from vsm; o dims = kq*16+tx
#pragma unroll
        for (int ck = 0; ck < 2; ++ck) {
            half8 vf = *(const half8*)(vsm + buf + krow + ck * 32 + quad * 8);
#pragma unroll
            for (int rt = 0; rt < 2; ++rt) {
                half8 af = *(const half8*)(psm + (h * 32 + rt * 16 + tx) * 72 + ck * 32 + quad * 8);
                o[rt] = __builtin_amdgcn_mfma_f32_16x16x32_f16(af, vf, o[rt], 0, 0, 0);
            }
        }
        if (t < 31) {
            *(uint4*)(ksm + (buf ^ 4608) + sdst) = gk2;
            *(uint4*)(vsm + (buf ^ 4608) + sdst) = gv;
        }
    }

    // store: wave owns rows h*32..+31 x dims kq*16..+15 (C-layout), fp32
#pragma unroll
    for (int rt = 0; rt < 2; ++rt)
#pragma unroll
        for (int r = 0; r < 4; ++r)
            out[((size_t)b * NS + q0 + h * 32 + rt * 16 + quad * 4 + r) * ND + kq * 16 + tx] =
                o[rt][r];
}

extern "C" void kernel_launch(void* const* d_in, const int* in_sizes, int n_in,
                              void* d_out, int out_size, void* d_ws, size_t ws_size,
                              hipStream_t stream) {
    const float* x  = (const float*)d_in[0];
    const float* Wq = (const float*)d_in[1];
    const float* bq = (const float*)d_in[2];
    const float* Wk = (const float*)d_in[3];
    const float* bk = (const float*)d_in[4];
    const float* Wv = (const float*)d_in[5];
    const float* bv = (const float*)d_in[6];

    _Float16* Qg = (_Float16*)d_ws;
    _Float16* Kg = Qg + (size_t)NB * NS * ND;
    _Float16* Vt = Kg + (size_t)NB * NS * ND;

    qkv_proj<<<NB * (NS / 16), 256, 0, stream>>>(x, Wq, bq, Wk, bk, Wv, bv, Qg, Kg, Vt);
    attn<<<NB * (NS / 64), 512, 0, stream>>>(Qg, Kg, Vt, (float*)d_out);
}